// Round 1
// baseline (208.161 us; speedup 1.0000x reference)
//
#include <hip/hip_runtime.h>

// InstanceRouteOptimizationArea — RUDY routing-demand map via impulse/cumsum trick.
//
// h_map[x,y] = sum_n dh_n * ox[n,x] * oy[n,y], where ox is the per-bin overlap
// of [xmin,xmax]. ox is the running cumsum of a sparse impulse vector:
// breakpoint at 'a' (bin j, frac f) -> imp[j] += BSX*(1-f), imp[j+1] += BSX*f
// (negated for the upper breakpoint). So the full map is a 2D cumsum of
// 16 bilinear corner splats per net per map -> 3.2e6 atomics total.

#define NB 256

__device__ __forceinline__ long long load_idx(const void* p, long long i, int is64) {
    if (is64) return ((const long long*)p)[i];
    return (long long)((const int*)p)[i];
}

__global__ void zero_kernel(float* g, int n) {
    int i = blockIdx.x * blockDim.x + threadIdx.x;
    int stride = gridDim.x * blockDim.x;
    for (; i < n; i += stride) g[i] = 0.0f;
}

__global__ void net_scatter(const float* __restrict__ pin_pos,
                            const float* __restrict__ net_weights,
                            const void* __restrict__ netpin_start,
                            const void* __restrict__ flat_netpin,
                            float* __restrict__ G, // [256][256][2] interleaved h,v
                            int num_nets, int num_pins) {
    int n = blockIdx.x * blockDim.x + threadIdx.x;
    if (n >= num_nets) return;
    // Detect int64 vs int32 index buffers: netpin_start[1]==4, so if the
    // second 32-bit word is 0 the buffer is little-endian int64.
    const int is64 = (((const int*)netpin_start)[1] == 0);
    long long s = load_idx(netpin_start, n, is64);
    long long e = load_idx(netpin_start, n + 1, is64);
    if (e <= s) return;

    float xmn = 3.0e38f, xmx = -3.0e38f, ymn = 3.0e38f, ymx = -3.0e38f;
    for (long long p = s; p < e; ++p) {
        long long pin = load_idx(flat_netpin, p, is64);
        float px = pin_pos[pin];
        float py = pin_pos[pin + num_pins];
        xmn = fminf(xmn, px); xmx = fmaxf(xmx, px);
        ymn = fminf(ymn, py); ymx = fmaxf(ymx, py);
    }
    float wx = xmx - xmn, wy = ymx - ymn;
    float area = fmaxf(wx * wy, 1e-6f);
    float w = net_weights[n];
    float dh = w * wx / area;
    float dv = w * wy / area;
    if (dh == 0.0f && dv == 0.0f) return;

    const float BSX = 3.90625f;
    const float INVB = 1.0f / 3.90625f;

    int jx[4]; float ax[4];
    int jy[4]; float ay[4];
    {
        float t, fj, f; int j;
        t = xmn * INVB; fj = floorf(t); j = (int)fj; f = t - fj;
        jx[0] = j;     ax[0] =  BSX * (1.0f - f);
        jx[1] = j + 1; ax[1] =  BSX * f;
        t = xmx * INVB; fj = floorf(t); j = (int)fj; f = t - fj;
        jx[2] = j;     ax[2] = -BSX * (1.0f - f);
        jx[3] = j + 1; ax[3] = -BSX * f;
        t = ymn * INVB; fj = floorf(t); j = (int)fj; f = t - fj;
        jy[0] = j;     ay[0] =  BSX * (1.0f - f);
        jy[1] = j + 1; ay[1] =  BSX * f;
        t = ymx * INVB; fj = floorf(t); j = (int)fj; f = t - fj;
        jy[2] = j;     ay[2] = -BSX * (1.0f - f);
        jy[3] = j + 1; ay[3] = -BSX * f;
    }

    // Impulses at index >= 256 can only affect bins >= 256 (never read): skip.
    #pragma unroll
    for (int b = 0; b < 4; ++b) {
        int y = jy[b];
        if (y < 0 || y >= NB) continue;
        float wyb = ay[b];
        #pragma unroll
        for (int a = 0; a < 4; ++a) {
            int x = jx[a];
            if (x < 0 || x >= NB) continue;
            float g = ax[a] * wyb;
            int base = (y * NB + x) * 2;
            atomicAdd(&G[base],     dh * g);
            atomicAdd(&G[base + 1], dv * g);
        }
    }
}

__global__ void row_scan(float2* G) {
    int y = blockIdx.x;
    int t = threadIdx.x;
    __shared__ float sh[NB];
    __shared__ float sv[NB];
    float2 v = G[y * NB + t];
    sh[t] = v.x; sv[t] = v.y;
    #pragma unroll
    for (int off = 1; off < NB; off <<= 1) {
        __syncthreads();
        float a = (t >= off) ? sh[t - off] : 0.0f;
        float b = (t >= off) ? sv[t - off] : 0.0f;
        __syncthreads();
        sh[t] += a; sv[t] += b;
    }
    __syncthreads();
    G[y * NB + t] = make_float2(sh[t], sv[t]);
}

__global__ void col_scan_util(const float2* __restrict__ G, float* __restrict__ util) {
    int x = threadIdx.x;
    const float INV_CH = 1.0f / (3.90625f * 3.90625f * 1.5625f);
    const float INV_CV = 1.0f / (3.90625f * 3.90625f * 1.45f);
    float rh = 0.0f, rv = 0.0f;
    for (int y = 0; y < NB; ++y) {
        float2 g = G[y * NB + x];
        rh += g.x; rv += g.y;
        float u = fmaxf(rh * INV_CH, rv * INV_CV);
        u = fminf(fmaxf(u, 0.5f), 2.0f);
        util[y * NB + x] = u;
    }
}

__global__ void instance_area(const float* __restrict__ pos,
                              const float* __restrict__ nsx,
                              const float* __restrict__ nsy,
                              const float* __restrict__ util,
                              float* __restrict__ out,
                              int num_movable, int num_nodes) {
    int i = blockIdx.x * blockDim.x + threadIdx.x;
    if (i >= num_movable) return;
    const float BSX = 3.90625f;
    const float INVB = 1.0f / 3.90625f;
    float x0f = pos[i];
    float y0f = pos[num_nodes + i];
    float x1f = x0f + nsx[i];
    float y1f = y0f + nsy[i];
    int kx0 = max(0, min(NB - 1, (int)floorf(x0f * INVB)));
    int kx1 = max(0, min(NB - 1, (int)floorf(x1f * INVB)));
    int ky0 = max(0, min(NB - 1, (int)floorf(y0f * INVB)));
    int ky1 = max(0, min(NB - 1, (int)floorf(y1f * INVB)));
    float acc = 0.0f;
    for (int ky = ky0; ky <= ky1; ++ky) {
        float by = ky * BSX;
        float ovy = fmaxf(fminf(y1f, by + BSX) - fmaxf(y0f, by), 0.0f);
        const float* urow = util + ky * NB;
        float accx = 0.0f;
        for (int kx = kx0; kx <= kx1; ++kx) {
            float bx = kx * BSX;
            float ovx = fmaxf(fminf(x1f, bx + BSX) - fmaxf(x0f, bx), 0.0f);
            accx += ovx * urow[kx];
        }
        acc += accx * ovy;
    }
    out[i] = acc;
}

extern "C" void kernel_launch(void* const* d_in, const int* in_sizes, int n_in,
                              void* d_out, int out_size, void* d_ws, size_t ws_size,
                              hipStream_t stream) {
    const float* pos         = (const float*)d_in[0];
    const float* pin_pos     = (const float*)d_in[1];
    const float* nsx         = (const float*)d_in[2];
    const float* nsy         = (const float*)d_in[3];
    const float* net_weights = (const float*)d_in[4];
    const void*  netpin_start = d_in[5];
    const void*  flat_netpin  = d_in[6];
    float* out = (float*)d_out;

    int num_pins    = in_sizes[1] / 2;
    int num_nodes   = in_sizes[2];
    int num_nets    = in_sizes[4];
    int num_movable = out_size;

    float* G    = (float*)d_ws;          // 256*256*2 floats (h,v interleaved)
    float* util = G + NB * NB * 2;       // 256*256 floats

    zero_kernel<<<256, 256, 0, stream>>>(G, NB * NB * 2);
    int gn = (num_nets + 255) / 256;
    net_scatter<<<gn, 256, 0, stream>>>(pin_pos, net_weights, netpin_start,
                                        flat_netpin, G, num_nets, num_pins);
    row_scan<<<NB, 256, 0, stream>>>((float2*)G);
    col_scan_util<<<1, 256, 0, stream>>>((const float2*)G, util);
    int gi = (num_movable + 255) / 256;
    instance_area<<<gi, 256, 0, stream>>>(pos, nsx, nsy, util, out,
                                          num_movable, num_nodes);
}

// Round 2
// 85.196 us; speedup vs baseline: 2.4433x; 2.4433x over previous
//
#include <hip/hip_runtime.h>

// InstanceRouteOptimizationArea — RUDY map via impulse/cumsum trick.
// Round 2: remove ALL device-scope atomics (round-1 profile: 98.6MB atomic
// write-through = 158µs of the 184µs net_scatter). New pipeline:
//   K1 bbox_kernel   : 4 threads/net, shfl-reduce bbox -> 32B record
//   K2 accum_kernel  : 32 y-windows x 8 net-chunks, LDS-tile accumulation
//   K3 reduce_scan   : sum 8 partials + row cumsum (Hillis)
//   K4 col_scan_util : column cumsum + clip
//   K5 instance_area : per-instance 3x3 bin dot product

#define NB 256
#define NW 8          // rows per accumulation window
#define NWIN 32       // NW*NWIN == NB
#define NCHUNK 8      // net chunks (partial grids)

__device__ __forceinline__ long long load_idx(const void* p, long long i, int is64) {
    if (is64) return ((const long long*)p)[i];
    return (long long)((const int*)p)[i];
}

// ---------------- K1: per-net bbox + densities ----------------
__global__ void bbox_kernel(const float* __restrict__ pin_pos,
                            const float* __restrict__ net_weights,
                            const void* __restrict__ netpin_start,
                            const void* __restrict__ flat_netpin,
                            float* __restrict__ rec,
                            int num_nets, int num_pins) {
    int gid = blockIdx.x * blockDim.x + threadIdx.x;
    int n = gid >> 2, k = gid & 3;
    if (n >= num_nets) return;
    const int is64 = (((const int*)netpin_start)[1] == 0);
    long long s = load_idx(netpin_start, n, is64);
    long long e = load_idx(netpin_start, n + 1, is64);
    float xmn = 3e38f, xmx = -3e38f, ymn = 3e38f, ymx = -3e38f;
    if (e - s == 4) {
        long long pin = load_idx(flat_netpin, s + k, is64);
        float px = pin_pos[pin], py = pin_pos[pin + num_pins];
        xmn = px; xmx = px; ymn = py; ymx = py;
    } else if (k == 0) {
        for (long long p = s; p < e; ++p) {
            long long pin = load_idx(flat_netpin, p, is64);
            float px = pin_pos[pin], py = pin_pos[pin + num_pins];
            xmn = fminf(xmn, px); xmx = fmaxf(xmx, px);
            ymn = fminf(ymn, py); ymx = fmaxf(ymx, py);
        }
    }
    #pragma unroll
    for (int m = 1; m <= 2; m <<= 1) {
        xmn = fminf(xmn, __shfl_xor(xmn, m));
        xmx = fmaxf(xmx, __shfl_xor(xmx, m));
        ymn = fminf(ymn, __shfl_xor(ymn, m));
        ymx = fmaxf(ymx, __shfl_xor(ymx, m));
    }
    if (k) return;
    float4* r = (float4*)(rec + 8LL * n);
    if (e <= s) {
        r[0] = make_float4(0.f, 0.f, 0.f, 0.f);
        r[1] = make_float4(0.f, 0.f, 0.f, 0.f);
        return;
    }
    float wx = xmx - xmn, wy = ymx - ymn;
    float area = fmaxf(wx * wy, 1e-6f);
    float w = net_weights[n];
    r[0] = make_float4(xmn, xmx, ymn, ymx);
    r[1] = make_float4(w * wx / area, w * wy / area, 0.f, 0.f);
}

// ---------------- K2: LDS-tile impulse accumulation ----------------
__global__ void accum_kernel(const float* __restrict__ rec,
                             float* __restrict__ P,
                             int num_nets) {
    __shared__ float acc[NW * NB * 2];
    const int win = blockIdx.x % NWIN;
    const int chunk = blockIdx.x / NWIN;
    const int r0 = win * NW;
    const int tid = threadIdx.x;
    for (int i = tid; i < NW * NB * 2; i += blockDim.x) acc[i] = 0.f;
    __syncthreads();
    const int c0 = (int)((long long)num_nets * chunk / NCHUNK);
    const int c1 = (int)((long long)num_nets * (chunk + 1) / NCHUNK);
    const float BSX = 3.90625f;
    const float INVB = 1.0f / 3.90625f;
    for (int n = c0 + tid; n < c1; n += blockDim.x) {
        float4 a = ((const float4*)rec)[2 * n];
        float4 b = ((const float4*)rec)[2 * n + 1];
        float ty0 = a.z * INVB, fj0 = floorf(ty0); int j0 = (int)fj0; float f0 = ty0 - fj0;
        float ty1 = a.w * INVB, fj1 = floorf(ty1); int j1 = (int)fj1; float f1 = ty1 - fj1;
        int   rr[4] = { j0, j0 + 1, j1, j1 + 1 };
        float rw[4] = { BSX * (1.f - f0), BSX * f0, -BSX * (1.f - f1), -BSX * f1 };
        bool any = false;
        #pragma unroll
        for (int q = 0; q < 4; ++q) any |= ((unsigned)(rr[q] - r0) < NW);
        if (!any) continue;
        float tx0 = a.x * INVB, g0 = floorf(tx0); int i0 = (int)g0; float h0 = tx0 - g0;
        float tx1 = a.y * INVB, g1 = floorf(tx1); int i1 = (int)g1; float h1 = tx1 - g1;
        int   jx[4] = { i0, i0 + 1, i1, i1 + 1 };
        float ax[4] = { BSX * (1.f - h0), BSX * h0, -BSX * (1.f - h1), -BSX * h1 };
        #pragma unroll
        for (int q = 0; q < 4; ++q) {
            int row = rr[q];
            if ((unsigned)(row - r0) >= NW) continue;
            float wr = rw[q];
            float* base = acc + (row - r0) * NB * 2;
            #pragma unroll
            for (int p = 0; p < 4; ++p) {
                int x = jx[p];
                if (x >= NB) continue;
                float g = ax[p] * wr;
                atomicAdd(base + 2 * x,     b.x * g);  // LDS atomic
                atomicAdd(base + 2 * x + 1, b.y * g);
            }
        }
    }
    __syncthreads();
    float* dst = P + ((long long)chunk * NB * NB + (long long)r0 * NB) * 2;
    for (int i = tid; i < NW * NB * 2; i += blockDim.x) dst[i] = acc[i];
}

// ---------------- K3: reduce partials + row cumsum ----------------
__global__ void reduce_scan(const float2* __restrict__ P, float2* __restrict__ G) {
    int y = blockIdx.x, t = threadIdx.x;
    float h = 0.f, v = 0.f;
    #pragma unroll
    for (int c = 0; c < NCHUNK; ++c) {
        float2 g = P[((long long)c * NB + y) * NB + t];
        h += g.x; v += g.y;
    }
    __shared__ float sh[NB];
    __shared__ float sv[NB];
    sh[t] = h; sv[t] = v;
    #pragma unroll
    for (int off = 1; off < NB; off <<= 1) {
        __syncthreads();
        float a = (t >= off) ? sh[t - off] : 0.0f;
        float b = (t >= off) ? sv[t - off] : 0.0f;
        __syncthreads();
        sh[t] += a; sv[t] += b;
    }
    __syncthreads();
    G[y * NB + t] = make_float2(sh[t], sv[t]);
}

// ---------------- K4: column cumsum + util ----------------
__global__ void col_scan_util(const float2* __restrict__ G, float* __restrict__ util) {
    int x = threadIdx.x;
    const float INV_CH = 1.0f / (3.90625f * 3.90625f * 1.5625f);
    const float INV_CV = 1.0f / (3.90625f * 3.90625f * 1.45f);
    float rh = 0.0f, rv = 0.0f;
    for (int y = 0; y < NB; ++y) {
        float2 g = G[y * NB + x];
        rh += g.x; rv += g.y;
        float u = fmaxf(rh * INV_CH, rv * INV_CV);
        u = fminf(fmaxf(u, 0.5f), 2.0f);
        util[y * NB + x] = u;
    }
}

// ---------------- K5: per-instance area ----------------
__global__ void instance_area(const float* __restrict__ pos,
                              const float* __restrict__ nsx,
                              const float* __restrict__ nsy,
                              const float* __restrict__ util,
                              float* __restrict__ out,
                              int num_movable, int num_nodes) {
    int i = blockIdx.x * blockDim.x + threadIdx.x;
    if (i >= num_movable) return;
    const float BSX = 3.90625f;
    const float INVB = 1.0f / 3.90625f;
    float x0f = pos[i];
    float y0f = pos[num_nodes + i];
    float x1f = x0f + nsx[i];
    float y1f = y0f + nsy[i];
    int kx0 = max(0, min(NB - 1, (int)floorf(x0f * INVB)));
    int kx1 = max(0, min(NB - 1, (int)floorf(x1f * INVB)));
    int ky0 = max(0, min(NB - 1, (int)floorf(y0f * INVB)));
    int ky1 = max(0, min(NB - 1, (int)floorf(y1f * INVB)));
    float acc = 0.0f;
    for (int ky = ky0; ky <= ky1; ++ky) {
        float by = ky * BSX;
        float ovy = fmaxf(fminf(y1f, by + BSX) - fmaxf(y0f, by), 0.0f);
        const float* urow = util + ky * NB;
        float accx = 0.0f;
        for (int kx = kx0; kx <= kx1; ++kx) {
            float bx = kx * BSX;
            float ovx = fmaxf(fminf(x1f, bx + BSX) - fmaxf(x0f, bx), 0.0f);
            accx += ovx * urow[kx];
        }
        acc += accx * ovy;
    }
    out[i] = acc;
}

// ---------------- Round-1 fallback (small workspace) ----------------
__global__ void zero_kernel(float* g, int n) {
    int i = blockIdx.x * blockDim.x + threadIdx.x;
    int stride = gridDim.x * blockDim.x;
    for (; i < n; i += stride) g[i] = 0.0f;
}

__global__ void net_scatter(const float* __restrict__ pin_pos,
                            const float* __restrict__ net_weights,
                            const void* __restrict__ netpin_start,
                            const void* __restrict__ flat_netpin,
                            float* __restrict__ G,
                            int num_nets, int num_pins) {
    int n = blockIdx.x * blockDim.x + threadIdx.x;
    if (n >= num_nets) return;
    const int is64 = (((const int*)netpin_start)[1] == 0);
    long long s = load_idx(netpin_start, n, is64);
    long long e = load_idx(netpin_start, n + 1, is64);
    if (e <= s) return;
    float xmn = 3e38f, xmx = -3e38f, ymn = 3e38f, ymx = -3e38f;
    for (long long p = s; p < e; ++p) {
        long long pin = load_idx(flat_netpin, p, is64);
        float px = pin_pos[pin];
        float py = pin_pos[pin + num_pins];
        xmn = fminf(xmn, px); xmx = fmaxf(xmx, px);
        ymn = fminf(ymn, py); ymx = fmaxf(ymx, py);
    }
    float wx = xmx - xmn, wy = ymx - ymn;
    float area = fmaxf(wx * wy, 1e-6f);
    float w = net_weights[n];
    float dh = w * wx / area;
    float dv = w * wy / area;
    const float BSX = 3.90625f;
    const float INVB = 1.0f / 3.90625f;
    int jx[4]; float ax[4];
    int jy[4]; float ay[4];
    {
        float t, fj, f; int j;
        t = xmn * INVB; fj = floorf(t); j = (int)fj; f = t - fj;
        jx[0] = j; ax[0] = BSX * (1.0f - f); jx[1] = j + 1; ax[1] = BSX * f;
        t = xmx * INVB; fj = floorf(t); j = (int)fj; f = t - fj;
        jx[2] = j; ax[2] = -BSX * (1.0f - f); jx[3] = j + 1; ax[3] = -BSX * f;
        t = ymn * INVB; fj = floorf(t); j = (int)fj; f = t - fj;
        jy[0] = j; ay[0] = BSX * (1.0f - f); jy[1] = j + 1; ay[1] = BSX * f;
        t = ymx * INVB; fj = floorf(t); j = (int)fj; f = t - fj;
        jy[2] = j; ay[2] = -BSX * (1.0f - f); jy[3] = j + 1; ay[3] = -BSX * f;
    }
    #pragma unroll
    for (int b = 0; b < 4; ++b) {
        int y = jy[b];
        if (y < 0 || y >= NB) continue;
        float wyb = ay[b];
        #pragma unroll
        for (int a = 0; a < 4; ++a) {
            int x = jx[a];
            if (x < 0 || x >= NB) continue;
            float g = ax[a] * wyb;
            int base = (y * NB + x) * 2;
            atomicAdd(&G[base],     dh * g);
            atomicAdd(&G[base + 1], dv * g);
        }
    }
}

extern "C" void kernel_launch(void* const* d_in, const int* in_sizes, int n_in,
                              void* d_out, int out_size, void* d_ws, size_t ws_size,
                              hipStream_t stream) {
    const float* pos          = (const float*)d_in[0];
    const float* pin_pos      = (const float*)d_in[1];
    const float* nsx          = (const float*)d_in[2];
    const float* nsy          = (const float*)d_in[3];
    const float* net_weights  = (const float*)d_in[4];
    const void*  netpin_start = d_in[5];
    const void*  flat_netpin  = d_in[6];
    float* out = (float*)d_out;

    int num_pins    = in_sizes[1] / 2;
    int num_nodes   = in_sizes[2];
    int num_nets    = in_sizes[4];
    int num_movable = out_size;

    size_t rec_f  = 8LL * num_nets;
    size_t part_f = (size_t)NCHUNK * NB * NB * 2;
    size_t g_f    = (size_t)NB * NB * 2;
    size_t u_f    = (size_t)NB * NB;
    size_t need   = (rec_f + part_f + g_f + u_f) * sizeof(float);

    if (ws_size >= need) {
        float* rec  = (float*)d_ws;
        float* P    = rec + rec_f;
        float* G    = P + part_f;
        float* util = G + g_f;

        int g1 = (4 * num_nets + 255) / 256;
        bbox_kernel<<<g1, 256, 0, stream>>>(pin_pos, net_weights, netpin_start,
                                            flat_netpin, rec, num_nets, num_pins);
        accum_kernel<<<NWIN * NCHUNK, 256, 0, stream>>>(rec, P, num_nets);
        reduce_scan<<<NB, 256, 0, stream>>>((const float2*)P, (float2*)G);
        col_scan_util<<<1, 256, 0, stream>>>((const float2*)G, util);
        int gi = (num_movable + 255) / 256;
        instance_area<<<gi, 256, 0, stream>>>(pos, nsx, nsy, util, out,
                                              num_movable, num_nodes);
    } else {
        // Fallback: round-1 path (needs 768KB workspace)
        float* G    = (float*)d_ws;
        float* util = G + NB * NB * 2;
        zero_kernel<<<256, 256, 0, stream>>>(G, NB * NB * 2);
        int gn = (num_nets + 255) / 256;
        net_scatter<<<gn, 256, 0, stream>>>(pin_pos, net_weights, netpin_start,
                                            flat_netpin, G, num_nets, num_pins);
        // reuse reduce_scan with NCHUNK=1 semantics via direct row scan
        reduce_scan<<<NB, 256, 0, stream>>>((const float2*)G, (float2*)G);
        col_scan_util<<<1, 256, 0, stream>>>((const float2*)G, util);
        int gi = (num_movable + 255) / 256;
        instance_area<<<gi, 256, 0, stream>>>(pos, nsx, nsy, util, out,
                                              num_movable, num_nodes);
    }
}

// Round 3
// 65.770 us; speedup vs baseline: 3.1650x; 1.2954x over previous
//
#include <hip/hip_runtime.h>

// InstanceRouteOptimizationArea — RUDY map via impulse/cumsum trick.
// Round 3: accum was latency-bound (occ 9.6%, 32x record replication).
//  - NW 8->32 (64KB LDS tile), replication x32 -> x8, hit ~25%
//  - split record: 8B ybounds for filter, 16B payload on hit only
//  - 512-thread accum blocks, ws-adaptive chunk count
//  - parallel column scan (256 blocks) replacing serial 1-block scan;
//    util stored transposed [x][y] for coalesced writes.

#define NB 256
#define NW 32         // rows per accumulation window
#define NWIN 8        // NB/NW
#define MAXCHUNK 32

__device__ __forceinline__ long long load_idx(const void* p, long long i, int is64) {
    if (is64) return ((const long long*)p)[i];
    return (long long)((const int*)p)[i];
}

// ---------------- K1: per-net bbox + densities ----------------
__global__ void bbox_kernel(const float* __restrict__ pin_pos,
                            const float* __restrict__ net_weights,
                            const void* __restrict__ netpin_start,
                            const void* __restrict__ flat_netpin,
                            float2* __restrict__ yb,
                            float4* __restrict__ rd,
                            int num_nets, int num_pins) {
    int gid = blockIdx.x * blockDim.x + threadIdx.x;
    int n = gid >> 2, k = gid & 3;
    if (n >= num_nets) return;
    const int is64 = (((const int*)netpin_start)[1] == 0);
    long long s = load_idx(netpin_start, n, is64);
    long long e = load_idx(netpin_start, n + 1, is64);
    float xmn = 3e38f, xmx = -3e38f, ymn = 3e38f, ymx = -3e38f;
    if (e - s == 4) {
        long long pin = load_idx(flat_netpin, s + k, is64);
        float px = pin_pos[pin], py = pin_pos[pin + num_pins];
        xmn = px; xmx = px; ymn = py; ymx = py;
    } else if (k == 0) {
        for (long long p = s; p < e; ++p) {
            long long pin = load_idx(flat_netpin, p, is64);
            float px = pin_pos[pin], py = pin_pos[pin + num_pins];
            xmn = fminf(xmn, px); xmx = fmaxf(xmx, px);
            ymn = fminf(ymn, py); ymx = fmaxf(ymx, py);
        }
    }
    #pragma unroll
    for (int m = 1; m <= 2; m <<= 1) {
        xmn = fminf(xmn, __shfl_xor(xmn, m));
        xmx = fmaxf(xmx, __shfl_xor(xmx, m));
        ymn = fminf(ymn, __shfl_xor(ymn, m));
        ymx = fmaxf(ymx, __shfl_xor(ymx, m));
    }
    if (k) return;
    if (e <= s) {
        yb[n] = make_float2(0.f, 0.f);
        rd[n] = make_float4(0.f, 0.f, 0.f, 0.f);
        return;
    }
    float wx = xmx - xmn, wy = ymx - ymn;
    float area = fmaxf(wx * wy, 1e-6f);
    float w = net_weights[n];
    yb[n] = make_float2(ymn, ymx);
    rd[n] = make_float4(xmn, xmx, w * wx / area, w * wy / area);
}

// ---------------- K2: LDS-tile impulse accumulation ----------------
__global__ void accum_kernel(const float2* __restrict__ yb,
                             const float4* __restrict__ rd,
                             float* __restrict__ P,
                             int num_nets, int nchunk) {
    __shared__ float acc[NW * NB * 2];   // 64 KiB
    const int win = blockIdx.x % NWIN;
    const int chunk = blockIdx.x / NWIN;
    const int r0 = win * NW;
    const int tid = threadIdx.x;
    const int bs = blockDim.x;
    for (int i = tid; i < NW * NB * 2; i += bs) acc[i] = 0.f;
    __syncthreads();
    const int c0 = (int)((long long)num_nets * chunk / nchunk);
    const int c1 = (int)((long long)num_nets * (chunk + 1) / nchunk);
    const float BSX = 3.90625f;
    const float INVB = 1.0f / 3.90625f;
    for (int n = c0 + tid; n < c1; n += bs) {
        float2 y = yb[n];
        float ty0 = y.x * INVB, fj0 = floorf(ty0); int j0 = (int)fj0; float f0 = ty0 - fj0;
        float ty1 = y.y * INVB, fj1 = floorf(ty1); int j1 = (int)fj1; float f1 = ty1 - fj1;
        // rows {j0,j0+1} or {j1,j1+1} intersect [r0, r0+NW) ?
        bool hit = ((unsigned)(j0 + 1 - r0) <= NW) || ((unsigned)(j1 + 1 - r0) <= NW);
        if (!hit) continue;
        float4 r = rd[n];
        float tx0 = r.x * INVB, g0 = floorf(tx0); int i0 = (int)g0; float h0 = tx0 - g0;
        float tx1 = r.y * INVB, g1 = floorf(tx1); int i1 = (int)g1; float h1 = tx1 - g1;
        int   jxs[4] = { i0, i0 + 1, i1, i1 + 1 };
        float axs[4] = { BSX * (1.f - h0), BSX * h0, -BSX * (1.f - h1), -BSX * h1 };
        int   rr[4]  = { j0, j0 + 1, j1, j1 + 1 };
        float rw[4]  = { BSX * (1.f - f0), BSX * f0, -BSX * (1.f - f1), -BSX * f1 };
        #pragma unroll
        for (int q = 0; q < 4; ++q) {
            int row = rr[q];
            if ((unsigned)(row - r0) >= NW) continue;
            float* base = acc + (row - r0) * (NB * 2);
            float wh = rw[q] * r.z;
            float wv = rw[q] * r.w;
            #pragma unroll
            for (int p = 0; p < 4; ++p) {
                int x = jxs[p];
                if (x >= NB) continue;
                atomicAdd(base + 2 * x,     axs[p] * wh);
                atomicAdd(base + 2 * x + 1, axs[p] * wv);
            }
        }
    }
    __syncthreads();
    float* dst = P + ((long long)chunk * NB * NB + (long long)r0 * NB) * 2;
    for (int i = tid; i < NW * NB * 2; i += bs) dst[i] = acc[i];
}

// ---------------- K3: reduce partials + row cumsum ----------------
__global__ void reduce_scan(const float2* __restrict__ P, float2* __restrict__ G,
                            int nchunk) {
    int y = blockIdx.x, t = threadIdx.x;
    float h = 0.f, v = 0.f;
    for (int c = 0; c < nchunk; ++c) {
        float2 g = P[((long long)c * NB + y) * NB + t];
        h += g.x; v += g.y;
    }
    __shared__ float sh[NB];
    __shared__ float sv[NB];
    sh[t] = h; sv[t] = v;
    #pragma unroll
    for (int off = 1; off < NB; off <<= 1) {
        __syncthreads();
        float a = (t >= off) ? sh[t - off] : 0.0f;
        float b = (t >= off) ? sv[t - off] : 0.0f;
        __syncthreads();
        sh[t] += a; sv[t] += b;
    }
    __syncthreads();
    G[y * NB + t] = make_float2(sh[t], sv[t]);
}

// ---------------- K4: parallel column cumsum + util (transposed store) ----
__global__ void col_scan_util(const float2* __restrict__ G, float* __restrict__ utilT) {
    int x = blockIdx.x, t = threadIdx.x;   // t indexes y
    const float INV_CH = 1.0f / (3.90625f * 3.90625f * 1.5625f);
    const float INV_CV = 1.0f / (3.90625f * 3.90625f * 1.45f);
    __shared__ float sh[NB];
    __shared__ float sv[NB];
    float2 g = G[t * NB + x];
    sh[t] = g.x; sv[t] = g.y;
    #pragma unroll
    for (int off = 1; off < NB; off <<= 1) {
        __syncthreads();
        float a = (t >= off) ? sh[t - off] : 0.0f;
        float b = (t >= off) ? sv[t - off] : 0.0f;
        __syncthreads();
        sh[t] += a; sv[t] += b;
    }
    __syncthreads();
    float u = fmaxf(sh[t] * INV_CH, sv[t] * INV_CV);
    u = fminf(fmaxf(u, 0.5f), 2.0f);
    utilT[x * NB + t] = u;   // [x][y], coalesced
}

// ---------------- K5: per-instance area (util transposed [x][y]) ----------
__global__ void instance_area(const float* __restrict__ pos,
                              const float* __restrict__ nsx,
                              const float* __restrict__ nsy,
                              const float* __restrict__ utilT,
                              float* __restrict__ out,
                              int num_movable, int num_nodes) {
    int i = blockIdx.x * blockDim.x + threadIdx.x;
    if (i >= num_movable) return;
    const float BSX = 3.90625f;
    const float INVB = 1.0f / 3.90625f;
    float x0f = pos[i];
    float y0f = pos[num_nodes + i];
    float x1f = x0f + nsx[i];
    float y1f = y0f + nsy[i];
    int kx0 = max(0, min(NB - 1, (int)floorf(x0f * INVB)));
    int kx1 = max(0, min(NB - 1, (int)floorf(x1f * INVB)));
    int ky0 = max(0, min(NB - 1, (int)floorf(y0f * INVB)));
    int ky1 = max(0, min(NB - 1, (int)floorf(y1f * INVB)));
    float acc = 0.0f;
    for (int kx = kx0; kx <= kx1; ++kx) {
        float bx = kx * BSX;
        float ovx = fmaxf(fminf(x1f, bx + BSX) - fmaxf(x0f, bx), 0.0f);
        const float* ucol = utilT + kx * NB;
        float accy = 0.0f;
        for (int ky = ky0; ky <= ky1; ++ky) {
            float by = ky * BSX;
            float ovy = fmaxf(fminf(y1f, by + BSX) - fmaxf(y0f, by), 0.0f);
            accy += ovy * ucol[ky];
        }
        acc += accy * ovx;
    }
    out[i] = acc;
}

extern "C" void kernel_launch(void* const* d_in, const int* in_sizes, int n_in,
                              void* d_out, int out_size, void* d_ws, size_t ws_size,
                              hipStream_t stream) {
    const float* pos          = (const float*)d_in[0];
    const float* pin_pos      = (const float*)d_in[1];
    const float* nsx          = (const float*)d_in[2];
    const float* nsy          = (const float*)d_in[3];
    const float* net_weights  = (const float*)d_in[4];
    const void*  netpin_start = d_in[5];
    const void*  flat_netpin  = d_in[6];
    float* out = (float*)d_out;

    int num_pins    = in_sizes[1] / 2;
    int num_nodes   = in_sizes[2];
    int num_nets    = in_sizes[4];
    int num_movable = out_size;

    // Workspace layout (floats): yb[2n] | rd[4n] | P[nchunk*131072] | G[131072] | util[65536]
    size_t yb_f   = 2LL * num_nets;
    size_t rd_f   = 4LL * num_nets;
    size_t grid_f = (size_t)NB * NB * 2;
    size_t util_f = (size_t)NB * NB;
    size_t fixed  = yb_f + rd_f + grid_f + util_f;
    long long avail = (long long)(ws_size / sizeof(float)) - (long long)fixed;
    int nchunk = (int)(avail / (long long)grid_f);
    if (nchunk < 1) nchunk = 1;
    if (nchunk > MAXCHUNK) nchunk = MAXCHUNK;

    float2* yb  = (float2*)d_ws;
    float4* rd  = (float4*)((float*)d_ws + yb_f);
    float*  P   = (float*)d_ws + yb_f + rd_f;
    float*  G   = P + (size_t)nchunk * grid_f;
    float*  ut  = G + grid_f;

    int g1 = (4 * num_nets + 255) / 256;
    bbox_kernel<<<g1, 256, 0, stream>>>(pin_pos, net_weights, netpin_start,
                                        flat_netpin, yb, rd, num_nets, num_pins);
    accum_kernel<<<NWIN * nchunk, 512, 0, stream>>>(yb, (const float4*)rd, P,
                                                    num_nets, nchunk);
    reduce_scan<<<NB, 256, 0, stream>>>((const float2*)P, (float2*)G, nchunk);
    col_scan_util<<<NB, 256, 0, stream>>>((const float2*)G, ut);
    int gi = (num_movable + 255) / 256;
    instance_area<<<gi, 256, 0, stream>>>(pos, nsx, nsy, ut, out,
                                          num_movable, num_nodes);
}